// Round 1
// baseline (217.455 us; speedup 1.0000x reference)
//
#include <hip/hip_runtime.h>

// IntraClusterGAT on MI355X — Round 7: 2-cluster software pipeline in attn.
//   prep:  Mtr = (WQ^T WK/8)^T, Pbf = hw*Wout@WV (bf16, in ws)
//   attn:  each block owns clusters 2b, 2b+1. Issue BOTH gathers up front
//          (ids then rows); convert c0 -> Xc, convert c1 -> 16KB bank-
//          interleaved LDS stage; compute c0 (GEMM1 Zc=Xc@M -> scores=Zc@Xc^T
//          -> exp -> shfl rowsum -> E-half stores interleaved with GEMM3
//          halves -> pk_add_bf16 atomic scatter); barrier; copy stage->Xc;
//          compute c1.  One exposed gather latency per 2 clusters; c0's
//          atomic drain overlaps c1's compute.
//   final: out = x + (accum@P^T)/max(cnt,1) + b  (128 rows/block, 1563 blocks)
//
// attn LDS = 54016B -> 3 blocks/CU (reg-limited at 3 anyway: ~96 acc + ~55
// arch; launch_bounds(256,3) keeps combined <= 170 -> 3 waves/SIMD).
// ws: accum_bf[NN*64] bf16 | countv[NN] f32 | Mtr 4096 bf16 | Pbf 4096 bf16

#define NV 100000
#define NN 200000
#define NCLUST 2048
#define XS 72    // Xc/Eh row stride (bf16): 144B, 16B-aligned

typedef __attribute__((ext_vector_type(8))) short short8;
typedef __attribute__((ext_vector_type(4))) unsigned uint4v;
typedef __attribute__((ext_vector_type(16))) float floatx16;

__device__ __forceinline__ unsigned short f2bf(float f) {
    union { float f; unsigned u; } v; v.f = f;
    unsigned r = v.u + 0x7fffu + ((v.u >> 16) & 1u);   // RNE
    return (unsigned short)(r >> 16);
}
__device__ __forceinline__ unsigned pack2bf(float lo, float hi) {
    union { float f; unsigned u; } a, b; a.f = lo; b.f = hi;
    unsigned ra = a.u + 0x7fffu + ((a.u >> 16) & 1u);
    unsigned rb = b.u + 0x7fffu + ((b.u >> 16) & 1u);
    return (ra >> 16) | (rb & 0xffff0000u);
}
__device__ __forceinline__ int crow(int r, int lane) {   // MFMA 32x32 C row map
    return (r & 3) + 8 * (r >> 2) + 4 * (lane >> 5);
}

__global__ __launch_bounds__(256) void prep_kernel(
    const float* __restrict__ WQ, const float* __restrict__ WK,
    const float* __restrict__ WV, const float* __restrict__ Wout,
    const float* __restrict__ head_weights, const int* __restrict__ active_heads_p,
    unsigned short* __restrict__ Mtr, unsigned short* __restrict__ Pbf)
{
    int o = blockIdx.x * blockDim.x + threadIdx.x;
    int ah = active_heads_p[0];
    float hw = 0.f;
    for (int i = 0; i < ah; ++i) hw += head_weights[i];
    hw /= (float)ah;
    if (o < 4096) {
        int d = o >> 6, a = o & 63;                       // Mtr[d][a] = M[a][d]
        float acc = 0.f;
        for (int j = 0; j < 64; ++j) acc += WQ[j*64 + a] * WK[j*64 + d];
        Mtr[o] = f2bf(acc * 0.125f);
    } else if (o < 8192) {
        int o2 = o - 4096;
        int j = o2 >> 6, b = o2 & 63;                     // Pbf[j][b]
        float acc = 0.f;
        for (int d = 0; d < 64; ++d) acc += Wout[j*64 + d] * WV[d*64 + b];
        Pbf[o2] = f2bf(acc * hw);
    }
}

// Full per-cluster compute: GEMM1 -> GEMM2 -> softmax -> (E-half | GEMM3)x2
// -> atomic scatter.  All state via LDS (Xc, Eh, ids, biascl) + Mtr via L1.
__device__ __forceinline__ void cluster_compute(
    unsigned short* Xc, unsigned short* Eh,
    const int* ids, const float* biascl,
    const unsigned short* __restrict__ Mtr,
    unsigned short* __restrict__ accum_bf,
    int lane, int w, int m, int hk)
{
    // ---- GEMM1: Zc = Xc @ M  (m-tile w, K=64; M frags from global/L1) ----
    {
        floatx16 z0 = {}, z1 = {};
        #pragma unroll
        for (int ks = 0; ks < 4; ++ks) {
            short8 mb0 = *(const short8*)(Mtr + m * 64 + ks * 16 + hk);
            short8 mb1 = *(const short8*)(Mtr + (32 + m) * 64 + ks * 16 + hk);
            short8 a = *(const short8*)&Xc[(w * 32 + m) * XS + ks * 16 + hk];
            z0 = __builtin_amdgcn_mfma_f32_32x32x16_bf16(a, mb0, z0, 0, 0, 0);
            z1 = __builtin_amdgcn_mfma_f32_32x32x16_bf16(a, mb1, z1, 0, 0, 0);
        }
        #pragma unroll
        for (int r = 0; r < 16; ++r) {     // wave-local rows 32w..32w+31
            int row = w * 32 + crow(r, lane);
            Eh[row * XS + m]      = f2bf(z0[r]);
            Eh[row * XS + 32 + m] = f2bf(z1[r]);
        }
    }

    // ---- GEMM2: scores = Zc @ Xc^T  (m-tile w, n-tiles 0..3, K=64) ----
    floatx16 sc[4] = {{}, {}, {}, {}};
    #pragma unroll
    for (int ks = 0; ks < 4; ++ks) {
        short8 a = *(const short8*)&Eh[(w * 32 + m) * XS + ks * 16 + hk];
        #pragma unroll
        for (int nt = 0; nt < 4; ++nt) {
            short8 b = *(const short8*)&Xc[(nt * 32 + m) * XS + ks * 16 + hk];
            sc[nt] = __builtin_amdgcn_mfma_f32_32x32x16_bf16(a, b, sc[nt], 0, 0, 0);
        }
    }

    // ---- bias + leaky_relu + exp + rowsum(shfl) + normalize (all fp32) ----
    const float b2 = biascl[m], b3 = biascl[32 + m];
    #pragma unroll
    for (int r = 0; r < 16; ++r) {
        float a0 = sc[0][r], a1 = sc[1][r], a2 = sc[2][r] + b2, a3 = sc[3][r] + b3;
        a0 = a0 > 0.f ? a0 : 0.2f * a0;
        a1 = a1 > 0.f ? a1 : 0.2f * a1;
        a2 = a2 > 0.f ? a2 : 0.2f * a2;
        a3 = a3 > 0.f ? a3 : 0.2f * a3;
        a0 = __expf(a0); a1 = __expf(a1); a2 = __expf(a2); a3 = __expf(a3);
        float s4 = (a0 + a1) + (a2 + a3);       // row's 32-col partial per lane
        #pragma unroll
        for (int off = 1; off < 32; off <<= 1) s4 += __shfl_xor(s4, off, 64);
        float inv = __builtin_amdgcn_rcpf(s4);  // full 128-col rowsum (half-wave)
        sc[0][r] = a0 * inv; sc[1][r] = a1 * inv;
        sc[2][r] = a2 * inv; sc[3][r] = a3 * inv;
    }

    // ---- E-half 1 (cols 0..63) over Zc rows (wave-local; in-order DS) ----
    #pragma unroll
    for (int r = 0; r < 16; ++r) {
        int row = w * 32 + crow(r, lane);
        Eh[row * XS + m]      = f2bf(sc[0][r]);
        Eh[row * XS + 32 + m] = f2bf(sc[1][r]);
    }

    // ---- GEMM3 half 1: t = 0..63 (B cols via ds_read_u16 from Xc) ----
    floatx16 g0 = {}, g1 = {};
    #pragma unroll
    for (int ks = 0; ks < 4; ++ks) {
        short8 a = *(const short8*)&Eh[(w * 32 + m) * XS + ks * 16 + hk];
        short8 b0, b1;
        #pragma unroll
        for (int j = 0; j < 8; ++j) {
            int t = ks * 16 + hk + j;
            b0[j] = (short)Xc[t * XS + m];
            b1[j] = (short)Xc[t * XS + 32 + m];
        }
        g0 = __builtin_amdgcn_mfma_f32_32x32x16_bf16(a, b0, g0, 0, 0, 0);
        g1 = __builtin_amdgcn_mfma_f32_32x32x16_bf16(a, b1, g1, 0, 0, 0);
    }

    // ---- E-half 2 (cols 64..127) ----
    #pragma unroll
    for (int r = 0; r < 16; ++r) {
        int row = w * 32 + crow(r, lane);
        Eh[row * XS + m]      = f2bf(sc[2][r]);
        Eh[row * XS + 32 + m] = f2bf(sc[3][r]);
    }

    // ---- GEMM3 half 2: t = 64..127 ----
    #pragma unroll
    for (int ks = 0; ks < 4; ++ks) {
        short8 a = *(const short8*)&Eh[(w * 32 + m) * XS + ks * 16 + hk];
        short8 b0, b1;
        #pragma unroll
        for (int j = 0; j < 8; ++j) {
            int t = 64 + ks * 16 + hk + j;
            b0[j] = (short)Xc[t * XS + m];
            b1[j] = (short)Xc[t * XS + 32 + m];
        }
        g0 = __builtin_amdgcn_mfma_f32_32x32x16_bf16(a, b0, g0, 0, 0, 0);
        g1 = __builtin_amdgcn_mfma_f32_32x32x16_bf16(a, b1, g1, 0, 0, 0);
    }

    // ---- pack adjacent cols (shfl_xor 1) + pk_add_bf16 scatter ----
    const bool ev = !(lane & 1);
    const int colbase = ev ? m : (31 + m);
    #pragma unroll
    for (int r = 0; r < 16; ++r) {
        int row = w * 32 + crow(r, lane);
        int nid = ids[row];
        float a0 = g0[r], a1 = g1[r];
        float t0 = __shfl_xor(a0, 1, 64);
        float t1 = __shfl_xor(a1, 1, 64);
        float lo = ev ? a0 : t1;
        float hi = ev ? t0 : a1;
        unsigned pk = (unsigned)f2bf(lo) | ((unsigned)f2bf(hi) << 16);
        unsigned long long addr =
            (unsigned long long)(accum_bf + (size_t)nid * 64 + colbase);
        asm volatile("global_atomic_pk_add_bf16 %0, %1, off"
                     :: "v"(addr), "v"(pk) : "memory");
    }
}

__global__ __launch_bounds__(256, 3) void attn_kernel(
    const float* __restrict__ x_var, const float* __restrict__ x_clause,
    const int* __restrict__ cvar, const int* __restrict__ ccl,
    const float* __restrict__ sat, const unsigned short* __restrict__ Mtr,
    unsigned short* __restrict__ accum_bf, float* __restrict__ countv)
{
    __shared__ unsigned short Xc[128 * XS];   // 18432, current cluster tile
    __shared__ unsigned short Eh[128 * XS];   // 18432, Zc then E-halves
    __shared__ unsigned stage4[16 * 256];     // 16384, next cluster (bank-interleaved)
    __shared__ int   ids[128];                //   512
    __shared__ float biascl[64];              //   256
    // total 54016 B -> 3 blocks/CU (matches the register-imposed limit)

    const int tid = threadIdx.x, lane = tid & 63, w = tid >> 6;
    const int m = lane & 31, hk = (lane >> 5) * 8;
    const int c0 = blockIdx.x * 2;            // this block owns c0, c0+1
    const int r = tid >> 1, half = tid & 1;

    // ---- ids for BOTH clusters (issued together -> one latency) ----
    int nid0, nid1;
    const float *src0, *src1;
    float satv0 = 0.f, satv1 = 0.f;
    if (r < 64) {
        nid0 = cvar[c0 * 64 + r];
        nid1 = cvar[c0 * 64 + 64 + r];        // cluster c0+1
        src0 = x_var + (size_t)nid0 * 64;
        src1 = x_var + (size_t)nid1 * 64;
    } else {
        int cid0 = ccl[c0 * 64 + (r - 64)];
        int cid1 = ccl[c0 * 64 + r];          // cluster c0+1
        nid0 = NV + cid0; nid1 = NV + cid1;
        src0 = x_clause + (size_t)cid0 * 64;
        src1 = x_clause + (size_t)cid1 * 64;
        if (half) { satv0 = sat[cid0]; satv1 = sat[cid1]; }
    }

    // ---- issue ALL 16 row loads (both clusters) back-to-back ----
    const float4* s40 = (const float4*)src0 + half * 8;
    const float4* s41 = (const float4*)src1 + half * 8;
    float4 v0[8], v1[8];
    #pragma unroll
    for (int i = 0; i < 8; ++i) v0[i] = s40[i];
    #pragma unroll
    for (int i = 0; i < 8; ++i) v1[i] = s41[i];

    if (!half) atomicAdd(&countv[nid0], 1.0f);

    // ---- c0 -> Xc (row-major bf16) ----
    {
        union { unsigned u[16]; short8 v[4]; } hb;
        #pragma unroll
        for (int i = 0; i < 8; ++i) {
            hb.u[2*i]   = pack2bf(v0[i].x, v0[i].y);
            hb.u[2*i+1] = pack2bf(v0[i].z, v0[i].w);
        }
        const int cb = half * 32;
        #pragma unroll
        for (int i = 0; i < 4; ++i) *(short8*)&Xc[r * XS + cb + i * 8] = hb.v[i];
    }
    // ---- c1 -> stage (dword i of this thread at stage4[i*256+tid]:
    //      lane-unique banks, conflict-free round trip) ----
    #pragma unroll
    for (int i = 0; i < 8; ++i) {
        stage4[(2*i)   * 256 + tid] = pack2bf(v1[i].x, v1[i].y);
        stage4[(2*i+1) * 256 + tid] = pack2bf(v1[i].z, v1[i].w);
    }
    if (!half) ids[r] = nid0;
    if (r >= 64 && half) biascl[r - 64] = satv0;
    __syncthreads();

    cluster_compute(Xc, Eh, ids, biascl, Mtr, accum_bf, lane, w, m, hk);
    __syncthreads();   // all waves done reading Xc/ids/biascl for c0

    // ---- c1: stage -> Xc (c0's atomic drain overlaps from here on) ----
    {
        const int cb = half * 32;
        #pragma unroll
        for (int j = 0; j < 4; ++j) {
            uint4v t;
            #pragma unroll
            for (int q = 0; q < 4; ++q) t[q] = stage4[(4*j + q) * 256 + tid];
            *(uint4v*)&Xc[r * XS + cb + 8 * j] = t;
        }
    }
    if (!half) { ids[r] = nid1; atomicAdd(&countv[nid1], 1.0f); }
    if (r >= 64 && half) biascl[r - 64] = satv1;
    __syncthreads();

    cluster_compute(Xc, Eh, ids, biascl, Mtr, accum_bf, lane, w, m, hk);
}

__global__ __launch_bounds__(256, 4) void finalize_kernel(
    const float* __restrict__ x_var, const float* __restrict__ x_clause,
    const unsigned short* __restrict__ accum_bf, const float* __restrict__ countv,
    const unsigned short* __restrict__ Pbf, const float* __restrict__ bout,
    float* __restrict__ out)
{
    __shared__ float cnts[128];
    const int tid = threadIdx.x, lane = tid & 63, w = tid >> 6;
    const int base = blockIdx.x * 128;        // 128 rows/block, 1 m-tile/wave
    if (tid < 128) {
        int n = base + tid;
        cnts[tid] = (n < NN) ? countv[n] : 1.f;
    }
    __syncthreads();

    const int m = lane & 31, hk = (lane >> 5) * 8;
    short8 pb[2][4];                              // P fragments via L1
    #pragma unroll
    for (int nt = 0; nt < 2; ++nt)
        #pragma unroll
        for (int ks = 0; ks < 4; ++ks)
            pb[nt][ks] = *(const short8*)(Pbf + (nt * 32 + m) * 64 + ks * 16 + hk);
    const float bias0 = bout[m], bias1 = bout[32 + m];

    const unsigned short* arow = accum_bf + (size_t)(base + w * 32 + m) * 64;
    floatx16 c0 = {}, c1 = {};
    #pragma unroll
    for (int ks = 0; ks < 4; ++ks) {
        short8 a = *(const short8*)(arow + ks * 16 + hk);
        c0 = __builtin_amdgcn_mfma_f32_32x32x16_bf16(a, pb[0][ks], c0, 0, 0, 0);
        c1 = __builtin_amdgcn_mfma_f32_32x32x16_bf16(a, pb[1][ks], c1, 0, 0, 0);
    }
    #pragma unroll
    for (int r = 0; r < 16; ++r) {
        int lrow = w * 32 + crow(r, lane);
        int n = base + lrow;
        if (n < NN) {
            float inv = 1.0f / fmaxf(cnts[lrow], 1.0f);
            const float* xs = (n < NV) ? (x_var + (size_t)n * 64)
                                       : (x_clause + (size_t)(n - NV) * 64);
            out[(size_t)n * 64 + m]      = xs[m]      + c0[r] * inv + bias0;
            out[(size_t)n * 64 + 32 + m] = xs[32 + m] + c1[r] * inv + bias1;
        }
    }
}

extern "C" void kernel_launch(void* const* d_in, const int* in_sizes, int n_in,
                              void* d_out, int out_size, void* d_ws, size_t ws_size,
                              hipStream_t stream)
{
    const float* x_var        = (const float*)d_in[0];
    const float* x_clause     = (const float*)d_in[1];
    const int*   cvar         = (const int*)d_in[4];
    const int*   ccl          = (const int*)d_in[5];
    const float* sat          = (const float*)d_in[6];
    const int*   active_heads = (const int*)d_in[7];
    const float* WQ           = (const float*)d_in[8];
    const float* WK           = (const float*)d_in[9];
    const float* WV           = (const float*)d_in[10];
    const float* head_weights = (const float*)d_in[11];
    const float* Wout         = (const float*)d_in[12];
    const float* bout         = (const float*)d_in[13];

    unsigned short* accum_bf = (unsigned short*)d_ws;          // NN*64 bf16
    float* countv = (float*)(accum_bf + (size_t)NN * 64);      // NN f32
    unsigned short* Mtr = (unsigned short*)(countv + NN);      // 4096 bf16
    unsigned short* Pbf = Mtr + 4096;                          // 4096 bf16

    hipMemsetAsync(accum_bf, 0, (size_t)NN * 64 * 2 + (size_t)NN * 4, stream);
    prep_kernel<<<32, 256, 0, stream>>>(WQ, WK, WV, Wout, head_weights, active_heads, Mtr, Pbf);
    attn_kernel<<<NCLUST / 2, 256, 0, stream>>>(x_var, x_clause, cvar, ccl, sat, Mtr, accum_bf, countv);
    finalize_kernel<<<(NN + 127) / 128, 256, 0, stream>>>(x_var, x_clause, accum_bf, countv, Pbf, bout, (float*)d_out);
}

// Round 2
// 214.528 us; speedup vs baseline: 1.0136x; 1.0136x over previous
//
#include <hip/hip_runtime.h>

// IntraClusterGAT on MI355X — Round 8: ping-pong 2-cluster pipeline, raw barriers.
//   prep:  Mtr = (WQ^T WK/8)^T, Pbf = hw*Wout@WV (bf16, in ws)
//   attn:  block owns clusters 2b, 2b+1. Gather BOTH up front; c0 -> bufA,
//          c1 held in 16 packed VGPRs. compute(c0): X=bufA, scratch=bufB;
//          after the last scratch A-read (GEMM3 h2), each wave writes its own
//          c1 rows into bufB (wave-local, in-order DS — no barrier needed),
//          then fires the atomic scatter. One raw s_barrier (lgkmcnt only, NO
//          vmcnt drain -> c0's atomics stay in flight), then compute(c1) with
//          X=bufB, scratch=bufA. 2 barriers/block, LDS 38.4KB -> 4 blocks/CU.
//   final: out = x + (accum@P^T)/max(cnt,1) + b  (256 rows/block, as R6)
//
// ws: accum_bf[NN*64] bf16 | countv[NN] f32 | Mtr 4096 bf16 | Pbf 4096 bf16

#define NV 100000
#define NN 200000
#define NCLUST 2048
#define XS 72    // X/E row stride (bf16): 144B, 16B-aligned, conflict-free

typedef __attribute__((ext_vector_type(8))) short short8;
typedef __attribute__((ext_vector_type(16))) float floatx16;

__device__ __forceinline__ unsigned short f2bf(float f) {
    union { float f; unsigned u; } v; v.f = f;
    unsigned r = v.u + 0x7fffu + ((v.u >> 16) & 1u);   // RNE
    return (unsigned short)(r >> 16);
}
__device__ __forceinline__ unsigned pack2bf(float lo, float hi) {
    union { float f; unsigned u; } a, b; a.f = lo; b.f = hi;
    unsigned ra = a.u + 0x7fffu + ((a.u >> 16) & 1u);
    unsigned rb = b.u + 0x7fffu + ((b.u >> 16) & 1u);
    return (ra >> 16) | (rb & 0xffff0000u);
}
__device__ __forceinline__ int crow(int r, int lane) {   // MFMA 32x32 C row map
    return (r & 3) + 8 * (r >> 2) + 4 * (lane >> 5);
}
// Barrier that orders LDS only: waves drain their own DS ops, then s_barrier.
// Global atomics (accum scatter, countv) intentionally stay in flight.
__device__ __forceinline__ void bar_lds() {
    __builtin_amdgcn_sched_barrier(0);
    asm volatile("s_waitcnt lgkmcnt(0)" ::: "memory");
    __builtin_amdgcn_s_barrier();
    __builtin_amdgcn_sched_barrier(0);
}

__global__ __launch_bounds__(256) void prep_kernel(
    const float* __restrict__ WQ, const float* __restrict__ WK,
    const float* __restrict__ WV, const float* __restrict__ Wout,
    const float* __restrict__ head_weights, const int* __restrict__ active_heads_p,
    unsigned short* __restrict__ Mtr, unsigned short* __restrict__ Pbf)
{
    int o = blockIdx.x * blockDim.x + threadIdx.x;
    int ah = active_heads_p[0];
    float hw = 0.f;
    for (int i = 0; i < ah; ++i) hw += head_weights[i];
    hw /= (float)ah;
    if (o < 4096) {
        int d = o >> 6, a = o & 63;                       // Mtr[d][a] = M[a][d]
        float acc = 0.f;
        for (int j = 0; j < 64; ++j) acc += WQ[j*64 + a] * WK[j*64 + d];
        Mtr[o] = f2bf(acc * 0.125f);
    } else if (o < 8192) {
        int o2 = o - 4096;
        int j = o2 >> 6, b = o2 & 63;                     // Pbf[j][b]
        float acc = 0.f;
        for (int d = 0; d < 64; ++d) acc += Wout[j*64 + d] * WV[d*64 + b];
        Pbf[o2] = f2bf(acc * hw);
    }
}

// Full per-cluster compute: GEMM1 -> GEMM2 -> softmax -> (E-half | GEMM3)x2
// -> [optional next-cluster X write into E buffer] -> atomic scatter.
template<bool WN>
__device__ __forceinline__ void cluster_compute(
    unsigned short* X, unsigned short* E,
    const int* ids, const float* biascl,
    const unsigned short* __restrict__ Mtr,
    unsigned short* __restrict__ accum_bf,
    int lane, int w, int m, int hk, int r, int cb,
    short8 nx0, short8 nx1, short8 nx2, short8 nx3)
{
    // ---- GEMM1: Z = X @ M  (m-tile w, K=64; M frags from global/L1) ----
    {
        floatx16 z0 = {}, z1 = {};
        #pragma unroll
        for (int ks = 0; ks < 4; ++ks) {
            short8 mb0 = *(const short8*)(Mtr + m * 64 + ks * 16 + hk);
            short8 mb1 = *(const short8*)(Mtr + (32 + m) * 64 + ks * 16 + hk);
            short8 a = *(const short8*)&X[(w * 32 + m) * XS + ks * 16 + hk];
            z0 = __builtin_amdgcn_mfma_f32_32x32x16_bf16(a, mb0, z0, 0, 0, 0);
            z1 = __builtin_amdgcn_mfma_f32_32x32x16_bf16(a, mb1, z1, 0, 0, 0);
        }
        #pragma unroll
        for (int rr = 0; rr < 16; ++rr) {   // wave-local rows 32w..32w+31
            int row = w * 32 + crow(rr, lane);
            E[row * XS + m]      = f2bf(z0[rr]);
            E[row * XS + 32 + m] = f2bf(z1[rr]);
        }
    }

    // ---- GEMM2: scores = Z @ X^T  (m-tile w, n-tiles 0..3, K=64) ----
    floatx16 sc[4] = {{}, {}, {}, {}};
    #pragma unroll
    for (int ks = 0; ks < 4; ++ks) {
        short8 a = *(const short8*)&E[(w * 32 + m) * XS + ks * 16 + hk];
        #pragma unroll
        for (int nt = 0; nt < 4; ++nt) {
            short8 b = *(const short8*)&X[(nt * 32 + m) * XS + ks * 16 + hk];
            sc[nt] = __builtin_amdgcn_mfma_f32_32x32x16_bf16(a, b, sc[nt], 0, 0, 0);
        }
    }

    // ---- bias + leaky_relu + exp + rowsum(shfl) + normalize (all fp32) ----
    const float b2 = biascl[m], b3 = biascl[32 + m];
    #pragma unroll
    for (int rr = 0; rr < 16; ++rr) {
        float a0 = sc[0][rr], a1 = sc[1][rr], a2 = sc[2][rr] + b2, a3 = sc[3][rr] + b3;
        a0 = a0 > 0.f ? a0 : 0.2f * a0;
        a1 = a1 > 0.f ? a1 : 0.2f * a1;
        a2 = a2 > 0.f ? a2 : 0.2f * a2;
        a3 = a3 > 0.f ? a3 : 0.2f * a3;
        a0 = __expf(a0); a1 = __expf(a1); a2 = __expf(a2); a3 = __expf(a3);
        float s4 = (a0 + a1) + (a2 + a3);       // row's 32-col partial per lane
        #pragma unroll
        for (int off = 1; off < 32; off <<= 1) s4 += __shfl_xor(s4, off, 64);
        float inv = __builtin_amdgcn_rcpf(s4);  // full 128-col rowsum (half-wave)
        sc[0][rr] = a0 * inv; sc[1][rr] = a1 * inv;
        sc[2][rr] = a2 * inv; sc[3][rr] = a3 * inv;
    }

    // ---- E-half 1 (cols 0..63) over Z rows (wave-local; in-order DS) ----
    #pragma unroll
    for (int rr = 0; rr < 16; ++rr) {
        int row = w * 32 + crow(rr, lane);
        E[row * XS + m]      = f2bf(sc[0][rr]);
        E[row * XS + 32 + m] = f2bf(sc[1][rr]);
    }

    // ---- GEMM3 half 1: t = 0..63 (B cols via ds_read_u16 from X) ----
    floatx16 g0 = {}, g1 = {};
    #pragma unroll
    for (int ks = 0; ks < 4; ++ks) {
        short8 a = *(const short8*)&E[(w * 32 + m) * XS + ks * 16 + hk];
        short8 b0, b1;
        #pragma unroll
        for (int j = 0; j < 8; ++j) {
            int t = ks * 16 + hk + j;
            b0[j] = (short)X[t * XS + m];
            b1[j] = (short)X[t * XS + 32 + m];
        }
        g0 = __builtin_amdgcn_mfma_f32_32x32x16_bf16(a, b0, g0, 0, 0, 0);
        g1 = __builtin_amdgcn_mfma_f32_32x32x16_bf16(a, b1, g1, 0, 0, 0);
    }

    // ---- E-half 2 (cols 64..127) ----
    #pragma unroll
    for (int rr = 0; rr < 16; ++rr) {
        int row = w * 32 + crow(rr, lane);
        E[row * XS + m]      = f2bf(sc[2][rr]);
        E[row * XS + 32 + m] = f2bf(sc[3][rr]);
    }

    // ---- GEMM3 half 2: t = 64..127 ----
    #pragma unroll
    for (int ks = 0; ks < 4; ++ks) {
        short8 a = *(const short8*)&E[(w * 32 + m) * XS + ks * 16 + hk];
        short8 b0, b1;
        #pragma unroll
        for (int j = 0; j < 8; ++j) {
            int t = 64 + ks * 16 + hk + j;
            b0[j] = (short)X[t * XS + m];
            b1[j] = (short)X[t * XS + 32 + m];
        }
        g0 = __builtin_amdgcn_mfma_f32_32x32x16_bf16(a, b0, g0, 0, 0, 0);
        g1 = __builtin_amdgcn_mfma_f32_32x32x16_bf16(a, b1, g1, 0, 0, 0);
    }

    // ---- park next cluster's X rows into E (wave-local rows; DS in-order
    //      guarantees these land after this wave's last E A-reads above) ----
    if (WN) {
        *(short8*)&E[r * XS + cb +  0] = nx0;
        *(short8*)&E[r * XS + cb +  8] = nx1;
        *(short8*)&E[r * XS + cb + 16] = nx2;
        *(short8*)&E[r * XS + cb + 24] = nx3;
    }

    // ---- pack adjacent cols (shfl_xor 1) + pk_add_bf16 scatter ----
    const bool ev = !(lane & 1);
    const int colbase = ev ? m : (31 + m);
    #pragma unroll
    for (int rr = 0; rr < 16; ++rr) {
        int row = w * 32 + crow(rr, lane);
        int nid = ids[row];
        float a0 = g0[rr], a1 = g1[rr];
        float t0 = __shfl_xor(a0, 1, 64);
        float t1 = __shfl_xor(a1, 1, 64);
        float lo = ev ? a0 : t1;
        float hi = ev ? t0 : a1;
        unsigned pk = (unsigned)f2bf(lo) | ((unsigned)f2bf(hi) << 16);
        unsigned long long addr =
            (unsigned long long)(accum_bf + (size_t)nid * 64 + colbase);
        asm volatile("global_atomic_pk_add_bf16 %0, %1, off"
                     :: "v"(addr), "v"(pk) : "memory");
    }
}

__global__ __launch_bounds__(256, 4) void attn_kernel(
    const float* __restrict__ x_var, const float* __restrict__ x_clause,
    const int* __restrict__ cvar, const int* __restrict__ ccl,
    const float* __restrict__ sat, const unsigned short* __restrict__ Mtr,
    unsigned short* __restrict__ accum_bf, float* __restrict__ countv)
{
    __shared__ unsigned short bufA[128 * XS];  // 18432
    __shared__ unsigned short bufB[128 * XS];  // 18432
    __shared__ int   ids0[128], ids1[128];     // 1024
    __shared__ float bias0[64], bias1[64];     // 512
    // total 38400 B -> 4 blocks/CU

    const int tid = threadIdx.x, lane = tid & 63, w = tid >> 6;
    const int m = lane & 31, hk = (lane >> 5) * 8;
    const int c0 = blockIdx.x * 2;             // this block owns c0, c0+1
    const int r = tid >> 1, half = tid & 1, cb = half * 32;

    // ---- ids for BOTH clusters (issued together -> one latency) ----
    int nid0, nid1;
    const float *src0, *src1;
    float sv0 = 0.f, sv1 = 0.f;
    if (r < 64) {
        nid0 = cvar[c0 * 64 + r];
        nid1 = cvar[c0 * 64 + 64 + r];         // cluster c0+1
        src0 = x_var + (size_t)nid0 * 64;
        src1 = x_var + (size_t)nid1 * 64;
    } else {
        int cid0 = ccl[c0 * 64 + (r - 64)];
        int cid1 = ccl[c0 * 64 + r];           // cluster c0+1
        nid0 = NV + cid0; nid1 = NV + cid1;
        src0 = x_clause + (size_t)cid0 * 64;
        src1 = x_clause + (size_t)cid1 * 64;
        if (half) { sv0 = sat[cid0]; sv1 = sat[cid1]; }
    }

    // ---- issue ALL 16 row loads (both clusters) back-to-back ----
    const float4* s40 = (const float4*)src0 + half * 8;
    const float4* s41 = (const float4*)src1 + half * 8;
    float4 v0[8], v1[8];
    #pragma unroll
    for (int i = 0; i < 8; ++i) v0[i] = s40[i];
    #pragma unroll
    for (int i = 0; i < 8; ++i) v1[i] = s41[i];

    if (!half) {
        ids0[r] = nid0; ids1[r] = nid1;
        atomicAdd(&countv[nid0], 1.0f);
        atomicAdd(&countv[nid1], 1.0f);
    }
    if (r >= 64 && half) { bias0[r - 64] = sv0; bias1[r - 64] = sv1; }

    // ---- c0 -> bufA (row-major bf16) ----
    {
        union { unsigned u[16]; short8 v[4]; } h0;
        #pragma unroll
        for (int i = 0; i < 8; ++i) {
            h0.u[2*i]   = pack2bf(v0[i].x, v0[i].y);
            h0.u[2*i+1] = pack2bf(v0[i].z, v0[i].w);
        }
        #pragma unroll
        for (int i = 0; i < 4; ++i) *(short8*)&bufA[r * XS + cb + i * 8] = h0.v[i];
    }
    // ---- c1 -> 16 packed VGPRs (held across c0 compute) ----
    union { unsigned u[16]; short8 v[4]; } h1;
    #pragma unroll
    for (int i = 0; i < 8; ++i) {
        h1.u[2*i]   = pack2bf(v1[i].x, v1[i].y);
        h1.u[2*i+1] = pack2bf(v1[i].z, v1[i].w);
    }

    bar_lds();   // bufA visible; countv/ids atomics may still fly

    // compute c0: X=bufA, scratch=bufB; park c1 rows into bufB near the end
    cluster_compute<true>(bufA, bufB, ids0, bias0, Mtr, accum_bf,
                          lane, w, m, hk, r, cb,
                          h1.v[0], h1.v[1], h1.v[2], h1.v[3]);

    bar_lds();   // all waves done reading bufA/bufB(c0); c1 X now in bufB.
                 // c0's atomic scatter intentionally still in flight.

    // compute c1: X=bufB, scratch=bufA
    short8 zz = {};
    cluster_compute<false>(bufB, bufA, ids1, bias1, Mtr, accum_bf,
                           lane, w, m, hk, r, cb, zz, zz, zz, zz);
}

__global__ __launch_bounds__(256, 4) void finalize_kernel(
    const float* __restrict__ x_var, const float* __restrict__ x_clause,
    const unsigned short* __restrict__ accum_bf, const float* __restrict__ countv,
    const unsigned short* __restrict__ Pbf, const float* __restrict__ bout,
    float* __restrict__ out)
{
    __shared__ float cnts[256];
    const int tid = threadIdx.x, lane = tid & 63, w = tid >> 6;
    const int base = blockIdx.x * 256;
    {
        int n = base + tid;
        cnts[tid] = (n < NN) ? countv[n] : 1.f;
    }
    __syncthreads();

    const int m = lane & 31, hk = (lane >> 5) * 8;
    short8 pb[2][4];                              // P fragments via L1
    #pragma unroll
    for (int nt = 0; nt < 2; ++nt)
        #pragma unroll
        for (int ks = 0; ks < 4; ++ks)
            pb[nt][ks] = *(const short8*)(Pbf + (nt * 32 + m) * 64 + ks * 16 + hk);
    const float bias0 = bout[m], bias1 = bout[32 + m];

    #pragma unroll
    for (int tm = 0; tm < 2; ++tm) {
        int mt = w * 2 + tm;                      // rows base+mt*32 ..
        const unsigned short* arow = accum_bf + (size_t)(base + mt * 32 + m) * 64;
        floatx16 c0 = {}, c1 = {};
        #pragma unroll
        for (int ks = 0; ks < 4; ++ks) {
            short8 a = *(const short8*)(arow + ks * 16 + hk);
            c0 = __builtin_amdgcn_mfma_f32_32x32x16_bf16(a, pb[0][ks], c0, 0, 0, 0);
            c1 = __builtin_amdgcn_mfma_f32_32x32x16_bf16(a, pb[1][ks], c1, 0, 0, 0);
        }
        #pragma unroll
        for (int rr = 0; rr < 16; ++rr) {
            int lrow = mt * 32 + crow(rr, lane);
            int n = base + lrow;
            if (n < NN) {
                float inv = 1.0f / fmaxf(cnts[lrow], 1.0f);
                const float* xs = (n < NV) ? (x_var + (size_t)n * 64)
                                           : (x_clause + (size_t)(n - NV) * 64);
                out[(size_t)n * 64 + m]      = xs[m]      + c0[rr] * inv + bias0;
                out[(size_t)n * 64 + 32 + m] = xs[32 + m] + c1[rr] * inv + bias1;
            }
        }
    }
}

extern "C" void kernel_launch(void* const* d_in, const int* in_sizes, int n_in,
                              void* d_out, int out_size, void* d_ws, size_t ws_size,
                              hipStream_t stream)
{
    const float* x_var        = (const float*)d_in[0];
    const float* x_clause     = (const float*)d_in[1];
    const int*   cvar         = (const int*)d_in[4];
    const int*   ccl          = (const int*)d_in[5];
    const float* sat          = (const float*)d_in[6];
    const int*   active_heads = (const int*)d_in[7];
    const float* WQ           = (const float*)d_in[8];
    const float* WK           = (const float*)d_in[9];
    const float* WV           = (const float*)d_in[10];
    const float* head_weights = (const float*)d_in[11];
    const float* Wout         = (const float*)d_in[12];
    const float* bout         = (const float*)d_in[13];

    unsigned short* accum_bf = (unsigned short*)d_ws;          // NN*64 bf16
    float* countv = (float*)(accum_bf + (size_t)NN * 64);      // NN f32
    unsigned short* Mtr = (unsigned short*)(countv + NN);      // 4096 bf16
    unsigned short* Pbf = Mtr + 4096;                          // 4096 bf16

    hipMemsetAsync(accum_bf, 0, (size_t)NN * 64 * 2 + (size_t)NN * 4, stream);
    prep_kernel<<<32, 256, 0, stream>>>(WQ, WK, WV, Wout, head_weights, active_heads, Mtr, Pbf);
    attn_kernel<<<NCLUST / 2, 256, 0, stream>>>(x_var, x_clause, cvar, ccl, sat, Mtr, accum_bf, countv);
    finalize_kernel<<<(NN + 255) / 256, 256, 0, stream>>>(x_var, x_clause, accum_bf, countv, Pbf, bout, (float*)d_out);
}